// Round 3
// baseline (1045.741 us; speedup 1.0000x reference)
//
#include <hip/hip_runtime.h>
#include <hip/hip_bf16.h>
#include <stdint.h>

#define T_TOK 2048
#define HDIM  2048
#define IDIM  1024
#define NEXP  16
#define SCALING 2.5f

typedef __attribute__((ext_vector_type(8))) short bf16x8;
typedef __attribute__((ext_vector_type(4))) float f32x4;

static __device__ __forceinline__ unsigned short f2bf(float f) {
    uint32_t u = __float_as_uint(f);
    u += 0x7FFF + ((u >> 16) & 1);
    return (unsigned short)(u >> 16);
}

#define GLD_LDS16(g, l) \
    __builtin_amdgcn_global_load_lds((const __attribute__((address_space(1))) uint32_t*)(g), \
                                     (__attribute__((address_space(3))) uint32_t*)(l), 16, 0, 0)

// ---------------- fp32 -> bf16 convert of hidden_states ----------------
__global__ __launch_bounds__(256) void cvt_k(const float* __restrict__ x,
                                             unsigned short* __restrict__ o) {
    int i = (blockIdx.x * 256 + threadIdx.x) * 8;
    float4 f0 = *(const float4*)(x + i);
    float4 f1 = *(const float4*)(x + i + 4);
    union { unsigned short h[8]; uint4 v; } u;
    u.h[0] = f2bf(f0.x); u.h[1] = f2bf(f0.y); u.h[2] = f2bf(f0.z); u.h[3] = f2bf(f0.w);
    u.h[4] = f2bf(f1.x); u.h[5] = f2bf(f1.y); u.h[6] = f2bf(f1.z); u.h[7] = f2bf(f1.w);
    *(uint4*)(o + i) = u.v;
}

// ---------------- weights -> bf16, gate/up interleaved ----------------
// wbf1[e][row][h], row = 2f + (0 gate / 1 up), e=16 is shared expert.
__global__ __launch_bounds__(256) void cvt_w1_k(const float* __restrict__ gate_w,
                                                const float* __restrict__ up_w,
                                                const float* __restrict__ shg,
                                                const float* __restrict__ shu,
                                                unsigned short* __restrict__ wbf1) {
    size_t flat = ((size_t)blockIdx.x * 256 + threadIdx.x) * 8;
    int e   = (int)(flat >> 22);            // 2048*2048 per expert
    int rem = (int)(flat & ((1u << 22) - 1));
    int row = rem >> 11;                    // H = 2048
    int h   = rem & 2047;
    int f   = row >> 1;
    const float* src;
    if (e == NEXP) src = (row & 1) ? shu : shg;
    else           src = ((row & 1) ? up_w : gate_w) + (size_t)e * (IDIM * HDIM);
    src += (size_t)f * HDIM + h;
    float4 f0 = *(const float4*)src;
    float4 f1 = *(const float4*)(src + 4);
    union { unsigned short s[8]; uint4 v; } u;
    u.s[0] = f2bf(f0.x); u.s[1] = f2bf(f0.y); u.s[2] = f2bf(f0.z); u.s[3] = f2bf(f0.w);
    u.s[4] = f2bf(f1.x); u.s[5] = f2bf(f1.y); u.s[6] = f2bf(f1.z); u.s[7] = f2bf(f1.w);
    *(uint4*)(wbf1 + flat) = u.v;
}

// wbf2[e][row][k], row over HDIM, k over IDIM; e=16 shared down.
__global__ __launch_bounds__(256) void cvt_w2_k(const float* __restrict__ down_w,
                                                const float* __restrict__ shd,
                                                unsigned short* __restrict__ wbf2) {
    size_t flat = ((size_t)blockIdx.x * 256 + threadIdx.x) * 8;
    int e   = (int)(flat >> 21);            // 2048*1024 per expert
    int rem = (int)(flat & ((1u << 21) - 1));
    const float* src = (e == NEXP) ? shd : (down_w + (size_t)e * (HDIM * IDIM));
    src += rem;
    float4 f0 = *(const float4*)src;
    float4 f1 = *(const float4*)(src + 4);
    union { unsigned short s[8]; uint4 v; } u;
    u.s[0] = f2bf(f0.x); u.s[1] = f2bf(f0.y); u.s[2] = f2bf(f0.z); u.s[3] = f2bf(f0.w);
    u.s[4] = f2bf(f1.x); u.s[5] = f2bf(f1.y); u.s[6] = f2bf(f1.z); u.s[7] = f2bf(f1.w);
    *(uint4*)(wbf2 + flat) = u.v;
}

// ---------------- routing (fp32 exact) ----------------
__global__ __launch_bounds__(256) void route_k(const float* __restrict__ x,
                                               const float* __restrict__ gw,
                                               const float* __restrict__ bias,
                                               int* __restrict__ tokl,
                                               float* __restrict__ twl,
                                               int* __restrict__ cnt) {
    __shared__ float slog[NEXP];
    int t = blockIdx.x;
    int tid = threadIdx.x;
    int e = tid >> 4, r = tid & 15;
    const float* xp = x + (size_t)t * HDIM;
    const float* wp = gw + (size_t)e * HDIM;
    float p = 0.f;
    for (int j = r; j < HDIM; j += 16) p += xp[j] * wp[j];
    for (int off = 8; off; off >>= 1) p += __shfl_down(p, off, 16);
    if (r == 0) slog[e] = p;
    __syncthreads();
    if (tid == 0) {
        float sc[NEXP], bi[NEXP];
        for (int i = 0; i < NEXP; i++) {
            sc[i] = 1.f / (1.f + expf(-slog[i]));
            bi[i] = sc[i] + bias[i];
        }
        float gsc[4];
        for (int g = 0; g < 4; g++) {
            float v0 = bi[g*4+0], v1 = bi[g*4+1], v2 = bi[g*4+2], v3 = bi[g*4+3];
            float hi01 = fmaxf(v0, v1), lo01 = fminf(v0, v1);
            float hi23 = fmaxf(v2, v3), lo23 = fminf(v2, v3);
            float top1 = fmaxf(hi01, hi23);
            float sec  = fmaxf(fminf(hi01, hi23), (hi01 >= hi23) ? lo01 : lo23);
            gsc[g] = top1 + sec;
        }
        int g0 = 0; for (int g = 1; g < 4; g++) if (gsc[g] > gsc[g0]) g0 = g;
        int g1 = (g0 == 0) ? 1 : 0;
        for (int g = 0; g < 4; g++) if (g != g0 && gsc[g] > gsc[g1]) g1 = g;
        float mk[NEXP];
        for (int i = 0; i < NEXP; i++) {
            int gg = i >> 2;
            mk[i] = (gg == g0 || gg == g1) ? bi[i] : -INFINITY;
        }
        int sel[4]; float wv[4]; float wsum = 0.f;
        for (int k = 0; k < 4; k++) {
            int bmax = 0; float bv = -INFINITY;
            for (int i = 0; i < NEXP; i++) if (mk[i] > bv) { bv = mk[i]; bmax = i; }
            sel[k] = bmax; mk[bmax] = -INFINITY;
            wv[k] = sc[bmax]; wsum += sc[bmax];
        }
        float scale = SCALING / (wsum + 1e-20f);
        for (int k = 0; k < 4; k++) {
            int ee = sel[k];
            int slot = atomicAdd(&cnt[ee], 1);
            tokl[ee * T_TOK + slot] = t;
            twl[ee * T_TOK + slot] = wv[k] * scale;
        }
    }
}

// ---------------- GEMM1: act = silu(Xe @ G^T) * (Xe @ U^T) ----------------
// grid: 17 * 16(mt) * 16(nt) = 4352; A gathered tokens, B from wbf1 (bf16).
__global__ __launch_bounds__(256) void gemm1_k(const unsigned short* __restrict__ Xbf,
                                               const unsigned short* __restrict__ wbf1,
                                               const int* __restrict__ tokl,
                                               const int* __restrict__ cnt,
                                               unsigned short* __restrict__ act) {
    __shared__ unsigned short lsA[2][128 * 64];
    __shared__ unsigned short lsB[2][128 * 64];
    int b = blockIdx.x;
    int swz = (b & 7) * 544 + (b >> 3);       // bijective XCD swizzle, 4352 = 8*544
    int mt = swz & 15, nt = (swz >> 4) & 15, e = swz >> 8;
    int C = (e == NEXP) ? T_TOK : cnt[e];
    int m0 = mt * 128;
    if (m0 >= C) return;
    int tid = threadIdx.x;

    int c8 = tid & 7, rr = tid >> 3;          // chunk-in-row, row-in-32
    int swzc = c8 ^ (rr & 7);
    const char* aA[4];
    const char* aB[4];
    for (int i = 0; i < 4; i++) {
        int slot = m0 + i * 32 + rr;
        int sl = (slot < C) ? slot : (C - 1);
        int tk = (e == NEXP) ? sl : tokl[e * T_TOK + sl];
        aA[i] = (const char*)Xbf + ((size_t)tk * HDIM + (size_t)swzc * 8) * 2;
        int brow = nt * 128 + i * 32 + rr;
        aB[i] = (const char*)wbf1 + (((size_t)e << 22) + (size_t)brow * HDIM + (size_t)swzc * 8) * 2;
    }

    int lane = tid & 63, wid = tid >> 6;
    int wrow = (wid >> 1) << 6, wcol = (wid & 1) << 6;
    int fr = lane & 15, kg = lane >> 4;

    f32x4 acc[4][4];
#pragma unroll
    for (int m = 0; m < 4; m++)
#pragma unroll
        for (int n = 0; n < 4; n++) acc[m][n] = (f32x4){0.f, 0.f, 0.f, 0.f};

    auto stage = [&](int kt, int bf) {
        size_t kb = (size_t)kt * 128;
#pragma unroll
        for (int i = 0; i < 4; i++)
            GLD_LDS16(aA[i] + kb, (char*)&lsA[bf][0] + i * 4096 + tid * 16);
#pragma unroll
        for (int i = 0; i < 4; i++)
            GLD_LDS16(aB[i] + kb, (char*)&lsB[bf][0] + i * 4096 + tid * 16);
    };
    auto compute = [&](int bf) {
        const char* lA = (const char*)&lsA[bf][0];
        const char* lB = (const char*)&lsB[bf][0];
#pragma unroll
        for (int h = 0; h < 2; h++) {
            bf16x8 av[4], bv[4];
#pragma unroll
            for (int m = 0; m < 4; m++)
                av[m] = *(const bf16x8*)(lA + (wrow + m * 16 + fr) * 128 + (((h * 4 + kg) ^ (fr & 7)) << 4));
#pragma unroll
            for (int n = 0; n < 4; n++)
                bv[n] = *(const bf16x8*)(lB + (wcol + n * 16 + fr) * 128 + (((h * 4 + kg) ^ (fr & 7)) << 4));
#pragma unroll
            for (int m = 0; m < 4; m++)
#pragma unroll
                for (int n = 0; n < 4; n++)
                    acc[m][n] = __builtin_amdgcn_mfma_f32_16x16x32_bf16(av[m], bv[n], acc[m][n], 0, 0, 0);
        }
    };

    stage(0, 0);
    __syncthreads();
    int cur = 0;
    for (int kt = 0; kt < 32; ++kt) {
        if (kt + 1 < 32) stage(kt + 1, cur ^ 1);
        compute(cur);
        __syncthreads();
        cur ^= 1;
    }

    unsigned short* actE = act + (size_t)e * T_TOK * IDIM;
#pragma unroll
    for (int m = 0; m < 4; m++)
#pragma unroll
        for (int n = 0; n < 4; n++)
#pragma unroll
            for (int q = 0; q < 4; q++) {
                float v = acc[m][n][q];
                float pu = __shfl_xor(v, 1, 64);
                int row = wrow + m * 16 + kg * 4 + q;
                int slot = m0 + row;
                int col = wcol + n * 16 + fr;
                if (!(lane & 1) && slot < C) {
                    float g = v, u = pu;
                    float a = g / (1.f + __expf(-g)) * u;
                    int j = nt * 64 + (col >> 1);
                    actE[(size_t)slot * IDIM + j] = f2bf(a);
                }
            }
}

// ---------------- GEMM2: out[tok] += w * (act_e @ D^T) ----------------
__global__ __launch_bounds__(256) void gemm2_k(const unsigned short* __restrict__ act,
                                               const unsigned short* __restrict__ wbf2,
                                               const int* __restrict__ tokl,
                                               const float* __restrict__ twl,
                                               const int* __restrict__ cnt,
                                               float* __restrict__ out) {
    __shared__ unsigned short lsA[2][128 * 64];
    __shared__ unsigned short lsB[2][128 * 64];
    int b = blockIdx.x;
    int swz = (b & 7) * 544 + (b >> 3);
    int mt = swz & 15, nt = (swz >> 4) & 15, e = swz >> 8;
    int C = (e == NEXP) ? T_TOK : cnt[e];
    int m0 = mt * 128;
    if (m0 >= C) return;
    int nb = nt * 128;
    int tid = threadIdx.x;

    const unsigned short* actE = act + (size_t)e * T_TOK * IDIM;
    int c8 = tid & 7, rr = tid >> 3;
    int swzc = c8 ^ (rr & 7);
    const char* aA[4];
    const char* aB[4];
    for (int i = 0; i < 4; i++) {
        int slot = m0 + i * 32 + rr;             // always < 2048; extra rows masked in epilogue
        aA[i] = (const char*)actE + ((size_t)slot * IDIM + (size_t)swzc * 8) * 2;
        aB[i] = (const char*)wbf2 + (((size_t)e << 21) + (size_t)(nb + i * 32 + rr) * IDIM + (size_t)swzc * 8) * 2;
    }

    int lane = tid & 63, wid = tid >> 6;
    int wrow = (wid >> 1) << 6, wcol = (wid & 1) << 6;
    int fr = lane & 15, kg = lane >> 4;

    f32x4 acc[4][4];
#pragma unroll
    for (int m = 0; m < 4; m++)
#pragma unroll
        for (int n = 0; n < 4; n++) acc[m][n] = (f32x4){0.f, 0.f, 0.f, 0.f};

    auto stage = [&](int kt, int bf) {
        size_t kb = (size_t)kt * 128;
#pragma unroll
        for (int i = 0; i < 4; i++)
            GLD_LDS16(aA[i] + kb, (char*)&lsA[bf][0] + i * 4096 + tid * 16);
#pragma unroll
        for (int i = 0; i < 4; i++)
            GLD_LDS16(aB[i] + kb, (char*)&lsB[bf][0] + i * 4096 + tid * 16);
    };
    auto compute = [&](int bf) {
        const char* lA = (const char*)&lsA[bf][0];
        const char* lB = (const char*)&lsB[bf][0];
#pragma unroll
        for (int h = 0; h < 2; h++) {
            bf16x8 av[4], bv[4];
#pragma unroll
            for (int m = 0; m < 4; m++)
                av[m] = *(const bf16x8*)(lA + (wrow + m * 16 + fr) * 128 + (((h * 4 + kg) ^ (fr & 7)) << 4));
#pragma unroll
            for (int n = 0; n < 4; n++)
                bv[n] = *(const bf16x8*)(lB + (wcol + n * 16 + fr) * 128 + (((h * 4 + kg) ^ (fr & 7)) << 4));
#pragma unroll
            for (int m = 0; m < 4; m++)
#pragma unroll
                for (int n = 0; n < 4; n++)
                    acc[m][n] = __builtin_amdgcn_mfma_f32_16x16x32_bf16(av[m], bv[n], acc[m][n], 0, 0, 0);
        }
    };

    stage(0, 0);
    __syncthreads();
    int cur = 0;
    for (int kt = 0; kt < 16; ++kt) {
        if (kt + 1 < 16) stage(kt + 1, cur ^ 1);
        compute(cur);
        __syncthreads();
        cur ^= 1;
    }

#pragma unroll
    for (int m = 0; m < 4; m++)
#pragma unroll
        for (int q = 0; q < 4; q++) {
            int row = wrow + m * 16 + kg * 4 + q;
            int slot = m0 + row;
            if (slot >= C) continue;
            int tk; float wg;
            if (e == NEXP) { tk = slot; wg = 1.f; }
            else { tk = tokl[e * T_TOK + slot]; wg = twl[e * T_TOK + slot]; }
            float* o = out + (size_t)tk * HDIM + nb + wcol + fr;
#pragma unroll
            for (int n = 0; n < 4; n++)
                atomicAdd(o + n * 16, wg * acc[m][n][q]);
        }
}

extern "C" void kernel_launch(void* const* d_in, const int* in_sizes, int n_in,
                              void* d_out, int out_size, void* d_ws, size_t ws_size,
                              hipStream_t stream) {
    const float* x      = (const float*)d_in[0];
    const float* gw     = (const float*)d_in[1];
    const float* bias   = (const float*)d_in[2];
    const float* gate_w = (const float*)d_in[3];
    const float* up_w   = (const float*)d_in[4];
    const float* down_w = (const float*)d_in[5];
    const float* shg    = (const float*)d_in[6];
    const float* shu    = (const float*)d_in[7];
    const float* shd    = (const float*)d_in[8];
    float* out = (float*)d_out;
    char* ws = (char*)d_ws;

    // ws layout (bytes)
    unsigned short* Xbf  = (unsigned short*)ws;                          // 8,388,608
    unsigned short* act  = (unsigned short*)(ws + 8388608ULL);           // 71,303,168
    unsigned short* wbf1 = (unsigned short*)(ws + 79691776ULL);          // 142,606,336
    unsigned short* wbf2 = (unsigned short*)(ws + 222298112ULL);         // 71,303,168
    int*            tokl = (int*)(ws + 293601280ULL);                    // 131,072
    float*          twl  = (float*)(ws + 293732352ULL);                  // 131,072
    int*            cnt  = (int*)(ws + 293863424ULL);                    // 64

    hipMemsetAsync(out, 0, (size_t)out_size * 4, stream);
    hipMemsetAsync(cnt, 0, 64, stream);
    cvt_k<<<2048, 256, 0, stream>>>(x, Xbf);
    cvt_w1_k<<<34816, 256, 0, stream>>>(gate_w, up_w, shg, shu, wbf1);
    cvt_w2_k<<<17408, 256, 0, stream>>>(down_w, shd, wbf2);
    route_k<<<2048, 256, 0, stream>>>(x, gw, bias, tokl, twl, cnt);
    gemm1_k<<<4352, 256, 0, stream>>>(Xbf, wbf1, tokl, cnt, act);
    gemm2_k<<<4352, 256, 0, stream>>>(act, wbf2, tokl, twl, cnt, out);
}

// Round 5
// 901.316 us; speedup vs baseline: 1.1602x; 1.1602x over previous
//
#include <hip/hip_runtime.h>
#include <hip/hip_bf16.h>
#include <stdint.h>

#define T_TOK 2048
#define HDIM  2048
#define IDIM  1024
#define NEXP  16
#define SCALING 2.5f

typedef __attribute__((ext_vector_type(8))) short bf16x8;
typedef __attribute__((ext_vector_type(4))) float f32x4;

static __device__ __forceinline__ unsigned short f2bf(float f) {
    uint32_t u = __float_as_uint(f);
    u += 0x7FFF + ((u >> 16) & 1);
    return (unsigned short)(u >> 16);
}

#define GLD_LDS16(g, l) \
    __builtin_amdgcn_global_load_lds((const __attribute__((address_space(1))) uint32_t*)(g), \
                                     (__attribute__((address_space(3))) uint32_t*)(l), 16, 0, 0)

// ---------------- fp32 -> bf16 convert of hidden_states ----------------
__global__ __launch_bounds__(256) void cvt_k(const float* __restrict__ x,
                                             unsigned short* __restrict__ o) {
    int i = (blockIdx.x * 256 + threadIdx.x) * 8;
    float4 f0 = *(const float4*)(x + i);
    float4 f1 = *(const float4*)(x + i + 4);
    union { unsigned short h[8]; uint4 v; } u;
    u.h[0] = f2bf(f0.x); u.h[1] = f2bf(f0.y); u.h[2] = f2bf(f0.z); u.h[3] = f2bf(f0.w);
    u.h[4] = f2bf(f1.x); u.h[5] = f2bf(f1.y); u.h[6] = f2bf(f1.z); u.h[7] = f2bf(f1.w);
    *(uint4*)(o + i) = u.v;
}

// ---------------- weights -> bf16, gate/up interleaved ----------------
__global__ __launch_bounds__(256) void cvt_w1_k(const float* __restrict__ gate_w,
                                                const float* __restrict__ up_w,
                                                const float* __restrict__ shg,
                                                const float* __restrict__ shu,
                                                unsigned short* __restrict__ wbf1) {
    size_t flat = ((size_t)blockIdx.x * 256 + threadIdx.x) * 8;
    int e   = (int)(flat >> 22);
    int rem = (int)(flat & ((1u << 22) - 1));
    int row = rem >> 11;
    int h   = rem & 2047;
    int f   = row >> 1;
    const float* src;
    if (e == NEXP) src = (row & 1) ? shu : shg;
    else           src = ((row & 1) ? up_w : gate_w) + (size_t)e * (IDIM * HDIM);
    src += (size_t)f * HDIM + h;
    float4 f0 = *(const float4*)src;
    float4 f1 = *(const float4*)(src + 4);
    union { unsigned short s[8]; uint4 v; } u;
    u.s[0] = f2bf(f0.x); u.s[1] = f2bf(f0.y); u.s[2] = f2bf(f0.z); u.s[3] = f2bf(f0.w);
    u.s[4] = f2bf(f1.x); u.s[5] = f2bf(f1.y); u.s[6] = f2bf(f1.z); u.s[7] = f2bf(f1.w);
    *(uint4*)(wbf1 + flat) = u.v;
}

__global__ __launch_bounds__(256) void cvt_w2_k(const float* __restrict__ down_w,
                                                const float* __restrict__ shd,
                                                unsigned short* __restrict__ wbf2) {
    size_t flat = ((size_t)blockIdx.x * 256 + threadIdx.x) * 8;
    int e   = (int)(flat >> 21);
    int rem = (int)(flat & ((1u << 21) - 1));
    const float* src = (e == NEXP) ? shd : (down_w + (size_t)e * (HDIM * IDIM));
    src += rem;
    float4 f0 = *(const float4*)src;
    float4 f1 = *(const float4*)(src + 4);
    union { unsigned short s[8]; uint4 v; } u;
    u.s[0] = f2bf(f0.x); u.s[1] = f2bf(f0.y); u.s[2] = f2bf(f0.z); u.s[3] = f2bf(f0.w);
    u.s[4] = f2bf(f1.x); u.s[5] = f2bf(f1.y); u.s[6] = f2bf(f1.z); u.s[7] = f2bf(f1.w);
    *(uint4*)(wbf2 + flat) = u.v;
}

// ---------------- routing (fp32 exact) ----------------
__global__ __launch_bounds__(256) void route_k(const float* __restrict__ x,
                                               const float* __restrict__ gw,
                                               const float* __restrict__ bias,
                                               int* __restrict__ tokl,
                                               float* __restrict__ twl,
                                               int* __restrict__ cnt) {
    __shared__ float slog[NEXP];
    int t = blockIdx.x;
    int tid = threadIdx.x;
    int e = tid >> 4, r = tid & 15;
    const float* xp = x + (size_t)t * HDIM;
    const float* wp = gw + (size_t)e * HDIM;
    float p = 0.f;
    for (int j = r; j < HDIM; j += 16) p += xp[j] * wp[j];
    for (int off = 8; off; off >>= 1) p += __shfl_down(p, off, 16);
    if (r == 0) slog[e] = p;
    __syncthreads();
    if (tid == 0) {
        float sc[NEXP], bi[NEXP];
        for (int i = 0; i < NEXP; i++) {
            sc[i] = 1.f / (1.f + expf(-slog[i]));
            bi[i] = sc[i] + bias[i];
        }
        float gsc[4];
        for (int g = 0; g < 4; g++) {
            float v0 = bi[g*4+0], v1 = bi[g*4+1], v2 = bi[g*4+2], v3 = bi[g*4+3];
            float hi01 = fmaxf(v0, v1), lo01 = fminf(v0, v1);
            float hi23 = fmaxf(v2, v3), lo23 = fminf(v2, v3);
            float top1 = fmaxf(hi01, hi23);
            float sec  = fmaxf(fminf(hi01, hi23), (hi01 >= hi23) ? lo01 : lo23);
            gsc[g] = top1 + sec;
        }
        int g0 = 0; for (int g = 1; g < 4; g++) if (gsc[g] > gsc[g0]) g0 = g;
        int g1 = (g0 == 0) ? 1 : 0;
        for (int g = 0; g < 4; g++) if (g != g0 && gsc[g] > gsc[g1]) g1 = g;
        float mk[NEXP];
        for (int i = 0; i < NEXP; i++) {
            int gg = i >> 2;
            mk[i] = (gg == g0 || gg == g1) ? bi[i] : -INFINITY;
        }
        int sel[4]; float wv[4]; float wsum = 0.f;
        for (int k = 0; k < 4; k++) {
            int bmax = 0; float bv = -INFINITY;
            for (int i = 0; i < NEXP; i++) if (mk[i] > bv) { bv = mk[i]; bmax = i; }
            sel[k] = bmax; mk[bmax] = -INFINITY;
            wv[k] = sc[bmax]; wsum += sc[bmax];
        }
        float scale = SCALING / (wsum + 1e-20f);
        for (int k = 0; k < 4; k++) {
            int ee = sel[k];
            int slot = atomicAdd(&cnt[ee], 1);
            tokl[ee * T_TOK + slot] = t;
            twl[ee * T_TOK + slot] = wv[k] * scale;
        }
    }
}

// ---------------- GEMM1: act = silu(Xe @ G^T) * (Xe @ U^T) ----------------
// 256x256 tile, BK=64, 8 waves (2Mx4N), deep pipeline w/ counted vmcnt.
// grid: 17 * 8(mt) * 8(nt) = 1088 blocks, 512 threads, 128KB dynamic LDS.
__global__ __launch_bounds__(512, 2) void gemm1_k(const unsigned short* __restrict__ Xbf,
                                                  const unsigned short* __restrict__ wbf1,
                                                  const int* __restrict__ tokl,
                                                  const int* __restrict__ cnt,
                                                  unsigned short* __restrict__ act) {
    extern __shared__ unsigned short sm[];   // [A0|A1|B0|B1] each 256*64
    int b = blockIdx.x;
    int swz = (b & 7) * 136 + (b >> 3);      // bijective, 1088 = 8*136
    int e = swz >> 6, mt = (swz >> 3) & 7, nt = swz & 7;
    int C = (e == NEXP) ? T_TOK : cnt[e];
    int m0 = mt * 256;
    if (m0 >= C) return;
    int tid = threadIdx.x;

    int c8 = tid & 7, rr = tid >> 3;         // chunk 0..7, row 0..63
    int swzc = c8 ^ (rr & 7);
    const char* aA[4];
    const char* aB[4];
#pragma unroll
    for (int i = 0; i < 4; i++) {
        int slot = m0 + i * 64 + rr;
        int sl = (slot < C) ? slot : (C - 1);
        int tk = (e == NEXP) ? sl : tokl[e * T_TOK + sl];
        aA[i] = (const char*)Xbf + ((size_t)tk * HDIM + (size_t)swzc * 8) * 2;
        int brow = nt * 256 + i * 64 + rr;
        aB[i] = (const char*)wbf1 + (((size_t)e << 22) + (size_t)brow * HDIM + (size_t)swzc * 8) * 2;
    }

    int lane = tid & 63, wid = tid >> 6;
    int wm = wid >> 2, wn = wid & 3;         // 2M x 4N waves
    int fr = lane & 15, kg = lane >> 4;
    int xo = fr & 7;

    f32x4 acc[8][4];
#pragma unroll
    for (int m = 0; m < 8; m++)
#pragma unroll
        for (int n = 0; n < 4; n++) acc[m][n] = (f32x4){0.f, 0.f, 0.f, 0.f};

    auto stage = [&](int kt, int bf) {
        size_t kb = (size_t)kt * 128;
        char* dA = (char*)(sm + bf * 16384);
        char* dB = (char*)(sm + 32768 + bf * 16384);
#pragma unroll
        for (int i = 0; i < 4; i++) GLD_LDS16(aA[i] + kb, dA + i * 8192 + tid * 16);
#pragma unroll
        for (int i = 0; i < 4; i++) GLD_LDS16(aB[i] + kb, dB + i * 8192 + tid * 16);
    };

    stage(0, 0);
    asm volatile("s_waitcnt vmcnt(0)" ::: "memory");
    __builtin_amdgcn_s_barrier();

    const int NT = 32;                        // K = 2048 / 64
    for (int kt = 0; kt < NT; ++kt) {
        int bf = kt & 1;
        __builtin_amdgcn_s_barrier();         // all waves done reading buf bf^1
        __builtin_amdgcn_sched_barrier(0);
        if (kt + 1 < NT) {
            stage(kt + 1, bf ^ 1);
            asm volatile("s_waitcnt vmcnt(8)" ::: "memory");   // tile kt staged
        } else {
            asm volatile("s_waitcnt vmcnt(0)" ::: "memory");
        }
        __builtin_amdgcn_s_barrier();         // tile kt visible to all waves
        __builtin_amdgcn_sched_barrier(0);

        const char* lA = (const char*)(sm + bf * 16384);
        const char* lB = (const char*)(sm + 32768 + bf * 16384);
        bf16x8 bv[4][2];
#pragma unroll
        for (int n = 0; n < 4; n++)
#pragma unroll
            for (int h = 0; h < 2; h++)
                bv[n][h] = *(const bf16x8*)(lB + (wn * 64 + n * 16 + fr) * 128 + ((((h << 2) | kg) ^ xo) << 4));
#pragma unroll
        for (int p = 0; p < 4; p++) {
            bf16x8 av[2][2];
#pragma unroll
            for (int mm = 0; mm < 2; mm++)
#pragma unroll
                for (int h = 0; h < 2; h++)
                    av[mm][h] = *(const bf16x8*)(lA + (wm * 128 + (p * 2 + mm) * 16 + fr) * 128 + ((((h << 2) | kg) ^ xo) << 4));
            asm volatile("s_waitcnt lgkmcnt(0)" ::: "memory");
            __builtin_amdgcn_sched_barrier(0);
            __builtin_amdgcn_s_setprio(1);
#pragma unroll
            for (int h = 0; h < 2; h++)
#pragma unroll
                for (int n = 0; n < 4; n++) {
                    acc[p * 2 + 0][n] = __builtin_amdgcn_mfma_f32_16x16x32_bf16(av[0][h], bv[n][h], acc[p * 2 + 0][n], 0, 0, 0);
                    acc[p * 2 + 1][n] = __builtin_amdgcn_mfma_f32_16x16x32_bf16(av[1][h], bv[n][h], acc[p * 2 + 1][n], 0, 0, 0);
                }
            __builtin_amdgcn_s_setprio(0);
        }
    }

    unsigned short* actE = act + (size_t)e * T_TOK * IDIM;
#pragma unroll
    for (int m = 0; m < 8; m++)
#pragma unroll
        for (int n = 0; n < 4; n++)
#pragma unroll
            for (int q = 0; q < 4; q++) {
                float v = acc[m][n][q];
                float pu = __shfl_xor(v, 1, 64);
                int slot = m0 + wm * 128 + m * 16 + kg * 4 + q;
                if (!(lane & 1) && slot < C) {
                    float g = v, u = pu;
                    float a = g / (1.f + __expf(-g)) * u;
                    int j = nt * 128 + wn * 32 + n * 8 + (fr >> 1);
                    actE[(size_t)slot * IDIM + j] = f2bf(a);
                }
            }
}

// ---------------- GEMM2: out[tok] += w * (act_e @ D^T) ----------------
__global__ __launch_bounds__(512, 2) void gemm2_k(const unsigned short* __restrict__ act,
                                                  const unsigned short* __restrict__ wbf2,
                                                  const int* __restrict__ tokl,
                                                  const float* __restrict__ twl,
                                                  const int* __restrict__ cnt,
                                                  float* __restrict__ out) {
    extern __shared__ unsigned short sm[];
    int b = blockIdx.x;
    int swz = (b & 7) * 136 + (b >> 3);
    int e = swz >> 6, mt = (swz >> 3) & 7, nt = swz & 7;
    int C = (e == NEXP) ? T_TOK : cnt[e];
    int m0 = mt * 256;
    if (m0 >= C) return;
    int nb = nt * 256;
    int tid = threadIdx.x;

    const unsigned short* actE = act + (size_t)e * T_TOK * IDIM;
    int c8 = tid & 7, rr = tid >> 3;
    int swzc = c8 ^ (rr & 7);
    const char* aA[4];
    const char* aB[4];
#pragma unroll
    for (int i = 0; i < 4; i++) {
        int slot = m0 + i * 64 + rr;          // < 2048; poison rows masked in epilogue
        aA[i] = (const char*)actE + ((size_t)slot * IDIM + (size_t)swzc * 8) * 2;
        aB[i] = (const char*)wbf2 + (((size_t)e << 21) + (size_t)(nb + i * 64 + rr) * IDIM + (size_t)swzc * 8) * 2;
    }

    int lane = tid & 63, wid = tid >> 6;
    int wm = wid >> 2, wn = wid & 3;
    int fr = lane & 15, kg = lane >> 4;
    int xo = fr & 7;

    f32x4 acc[8][4];
#pragma unroll
    for (int m = 0; m < 8; m++)
#pragma unroll
        for (int n = 0; n < 4; n++) acc[m][n] = (f32x4){0.f, 0.f, 0.f, 0.f};

    auto stage = [&](int kt, int bf) {
        size_t kb = (size_t)kt * 128;
        char* dA = (char*)(sm + bf * 16384);
        char* dB = (char*)(sm + 32768 + bf * 16384);
#pragma unroll
        for (int i = 0; i < 4; i++) GLD_LDS16(aA[i] + kb, dA + i * 8192 + tid * 16);
#pragma unroll
        for (int i = 0; i < 4; i++) GLD_LDS16(aB[i] + kb, dB + i * 8192 + tid * 16);
    };

    stage(0, 0);
    asm volatile("s_waitcnt vmcnt(0)" ::: "memory");
    __builtin_amdgcn_s_barrier();

    const int NT = 16;                        // K = 1024 / 64
    for (int kt = 0; kt < NT; ++kt) {
        int bf = kt & 1;
        __builtin_amdgcn_s_barrier();
        __builtin_amdgcn_sched_barrier(0);
        if (kt + 1 < NT) {
            stage(kt + 1, bf ^ 1);
            asm volatile("s_waitcnt vmcnt(8)" ::: "memory");
        } else {
            asm volatile("s_waitcnt vmcnt(0)" ::: "memory");
        }
        __builtin_amdgcn_s_barrier();
        __builtin_amdgcn_sched_barrier(0);

        const char* lA = (const char*)(sm + bf * 16384);
        const char* lB = (const char*)(sm + 32768 + bf * 16384);
        bf16x8 bv[4][2];
#pragma unroll
        for (int n = 0; n < 4; n++)
#pragma unroll
            for (int h = 0; h < 2; h++)
                bv[n][h] = *(const bf16x8*)(lB + (wn * 64 + n * 16 + fr) * 128 + ((((h << 2) | kg) ^ xo) << 4));
#pragma unroll
        for (int p = 0; p < 4; p++) {
            bf16x8 av[2][2];
#pragma unroll
            for (int mm = 0; mm < 2; mm++)
#pragma unroll
                for (int h = 0; h < 2; h++)
                    av[mm][h] = *(const bf16x8*)(lA + (wm * 128 + (p * 2 + mm) * 16 + fr) * 128 + ((((h << 2) | kg) ^ xo) << 4));
            asm volatile("s_waitcnt lgkmcnt(0)" ::: "memory");
            __builtin_amdgcn_sched_barrier(0);
            __builtin_amdgcn_s_setprio(1);
#pragma unroll
            for (int h = 0; h < 2; h++)
#pragma unroll
                for (int n = 0; n < 4; n++) {
                    acc[p * 2 + 0][n] = __builtin_amdgcn_mfma_f32_16x16x32_bf16(av[0][h], bv[n][h], acc[p * 2 + 0][n], 0, 0, 0);
                    acc[p * 2 + 1][n] = __builtin_amdgcn_mfma_f32_16x16x32_bf16(av[1][h], bv[n][h], acc[p * 2 + 1][n], 0, 0, 0);
                }
            __builtin_amdgcn_s_setprio(0);
        }
    }

#pragma unroll
    for (int m = 0; m < 8; m++)
#pragma unroll
        for (int q = 0; q < 4; q++) {
            int slot = m0 + wm * 128 + m * 16 + kg * 4 + q;
            if (slot >= C) continue;
            int tk; float wg;
            if (e == NEXP) { tk = slot; wg = 1.f; }
            else { tk = tokl[e * T_TOK + slot]; wg = twl[e * T_TOK + slot]; }
            float* o = out + (size_t)tk * HDIM + nb + wn * 64 + fr;
#pragma unroll
            for (int n = 0; n < 4; n++)
                atomicAdd(o + n * 16, wg * acc[m][n][q]);
        }
}

extern "C" void kernel_launch(void* const* d_in, const int* in_sizes, int n_in,
                              void* d_out, int out_size, void* d_ws, size_t ws_size,
                              hipStream_t stream) {
    const float* x      = (const float*)d_in[0];
    const float* gw     = (const float*)d_in[1];
    const float* bias   = (const float*)d_in[2];
    const float* gate_w = (const float*)d_in[3];
    const float* up_w   = (const float*)d_in[4];
    const float* down_w = (const float*)d_in[5];
    const float* shg    = (const float*)d_in[6];
    const float* shu    = (const float*)d_in[7];
    const float* shd    = (const float*)d_in[8];
    float* out = (float*)d_out;
    char* ws = (char*)d_ws;

    unsigned short* Xbf  = (unsigned short*)ws;                          // 8,388,608
    unsigned short* act  = (unsigned short*)(ws + 8388608ULL);           // 71,303,168
    unsigned short* wbf1 = (unsigned short*)(ws + 79691776ULL);          // 142,606,336
    unsigned short* wbf2 = (unsigned short*)(ws + 222298112ULL);         // 71,303,168
    int*            tokl = (int*)(ws + 293601280ULL);                    // 131,072
    float*          twl  = (float*)(ws + 293732352ULL);                  // 131,072
    int*            cnt  = (int*)(ws + 293863424ULL);                    // 64

    static bool attr_set = false;
    if (!attr_set) {
        hipFuncSetAttribute((const void*)gemm1_k, hipFuncAttributeMaxDynamicSharedMemorySize, 131072);
        hipFuncSetAttribute((const void*)gemm2_k, hipFuncAttributeMaxDynamicSharedMemorySize, 131072);
        attr_set = true;
    }

    hipMemsetAsync(out, 0, (size_t)out_size * 4, stream);
    hipMemsetAsync(cnt, 0, 64, stream);
    cvt_k<<<2048, 256, 0, stream>>>(x, Xbf);
    cvt_w1_k<<<34816, 256, 0, stream>>>(gate_w, up_w, shg, shu, wbf1);
    cvt_w2_k<<<17408, 256, 0, stream>>>(down_w, shd, wbf2);
    route_k<<<2048, 256, 0, stream>>>(x, gw, bias, tokl, twl, cnt);
    gemm1_k<<<1088, 512, 131072, stream>>>(Xbf, wbf1, tokl, cnt, act);
    gemm2_k<<<1088, 512, 131072, stream>>>(act, wbf2, tokl, twl, cnt, out);
}

// Round 6
// 843.896 us; speedup vs baseline: 1.2392x; 1.0680x over previous
//
#include <hip/hip_runtime.h>
#include <hip/hip_bf16.h>
#include <stdint.h>

#define T_TOK 2048
#define HDIM  2048
#define IDIM  1024
#define NEXP  16
#define SCALING 2.5f

typedef __attribute__((ext_vector_type(8))) short bf16x8;
typedef __attribute__((ext_vector_type(4))) float f32x4;

static __device__ __forceinline__ unsigned short f2bf(float f) {
    uint32_t u = __float_as_uint(f);
    u += 0x7FFF + ((u >> 16) & 1);
    return (unsigned short)(u >> 16);
}

#define GLD_LDS16(g, l) \
    __builtin_amdgcn_global_load_lds((const __attribute__((address_space(1))) uint32_t*)(g), \
                                     (__attribute__((address_space(3))) uint32_t*)(l), 16, 0, 0)

// ---------------- all weights -> bf16 (gate/up interleaved; down) ----------------
__global__ __launch_bounds__(256) void cvtw_k(const float* __restrict__ gate_w,
                                              const float* __restrict__ up_w,
                                              const float* __restrict__ shg,
                                              const float* __restrict__ shu,
                                              const float* __restrict__ down_w,
                                              const float* __restrict__ shd,
                                              unsigned short* __restrict__ wbf1,
                                              unsigned short* __restrict__ wbf2) {
    int b = blockIdx.x;
    const float* src;
    unsigned short* dst;
    size_t flat;
    if (b < 34816) {                        // gate/up: 17 * 4M elems
        flat = ((size_t)b * 256 + threadIdx.x) * 8;
        int e   = (int)(flat >> 22);
        int rem = (int)(flat & ((1u << 22) - 1));
        int row = rem >> 11;
        int h   = rem & 2047;
        int f   = row >> 1;
        if (e == NEXP) src = (row & 1) ? shu : shg;
        else           src = ((row & 1) ? up_w : gate_w) + (size_t)e * (IDIM * HDIM);
        src += (size_t)f * HDIM + h;
        dst = wbf1 + flat;
    } else {                                // down: 17 * 2M elems
        flat = ((size_t)(b - 34816) * 256 + threadIdx.x) * 8;
        int e   = (int)(flat >> 21);
        int rem = (int)(flat & ((1u << 21) - 1));
        src = ((e == NEXP) ? shd : (down_w + (size_t)e * (HDIM * IDIM))) + rem;
        dst = wbf2 + flat;
    }
    float4 f0 = *(const float4*)src;
    float4 f1 = *(const float4*)(src + 4);
    union { unsigned short s[8]; uint4 v; } u;
    u.s[0] = f2bf(f0.x); u.s[1] = f2bf(f0.y); u.s[2] = f2bf(f0.z); u.s[3] = f2bf(f0.w);
    u.s[4] = f2bf(f1.x); u.s[5] = f2bf(f1.y); u.s[6] = f2bf(f1.z); u.s[7] = f2bf(f1.w);
    *(uint4*)dst = u.v;
}

// ---------------- fused: x->bf16 + routing (fp32 exact) ----------------
__global__ __launch_bounds__(256) void route2_k(const float* __restrict__ x,
                                                const float* __restrict__ gw,
                                                const float* __restrict__ bias,
                                                unsigned short* __restrict__ Xbf,
                                                int* __restrict__ tokl,
                                                float* __restrict__ twl,
                                                int* __restrict__ cnt,
                                                int* __restrict__ sl4) {
    __shared__ float sx[HDIM];
    __shared__ float slog[NEXP];
    int t = blockIdx.x;
    int tid = threadIdx.x;
    const float* xp = x + (size_t)t * HDIM;
    float4 f0 = *(const float4*)(xp + tid * 8);
    float4 f1 = *(const float4*)(xp + tid * 8 + 4);
    union { unsigned short h[8]; uint4 v; } u;
    u.h[0] = f2bf(f0.x); u.h[1] = f2bf(f0.y); u.h[2] = f2bf(f0.z); u.h[3] = f2bf(f0.w);
    u.h[4] = f2bf(f1.x); u.h[5] = f2bf(f1.y); u.h[6] = f2bf(f1.z); u.h[7] = f2bf(f1.w);
    *(uint4*)(Xbf + (size_t)t * HDIM + tid * 8) = u.v;
    *(float4*)(sx + tid * 8) = f0;
    *(float4*)(sx + tid * 8 + 4) = f1;
    __syncthreads();
    int e = tid >> 4, r = tid & 15;
    const float* wp = gw + (size_t)e * HDIM;
    float p = 0.f;
    for (int j = r; j < HDIM; j += 16) p += sx[j] * wp[j];
    for (int off = 8; off; off >>= 1) p += __shfl_down(p, off, 16);
    if (r == 0) slog[e] = p;
    __syncthreads();
    if (tid == 0) {
        float sc[NEXP], bi[NEXP];
        for (int i = 0; i < NEXP; i++) {
            sc[i] = 1.f / (1.f + expf(-slog[i]));
            bi[i] = sc[i] + bias[i];
        }
        float gsc[4];
        for (int g = 0; g < 4; g++) {
            float v0 = bi[g*4+0], v1 = bi[g*4+1], v2 = bi[g*4+2], v3 = bi[g*4+3];
            float hi01 = fmaxf(v0, v1), lo01 = fminf(v0, v1);
            float hi23 = fmaxf(v2, v3), lo23 = fminf(v2, v3);
            float top1 = fmaxf(hi01, hi23);
            float sec  = fmaxf(fminf(hi01, hi23), (hi01 >= hi23) ? lo01 : lo23);
            gsc[g] = top1 + sec;
        }
        int g0 = 0; for (int g = 1; g < 4; g++) if (gsc[g] > gsc[g0]) g0 = g;
        int g1 = (g0 == 0) ? 1 : 0;
        for (int g = 0; g < 4; g++) if (g != g0 && gsc[g] > gsc[g1]) g1 = g;
        float mk[NEXP];
        for (int i = 0; i < NEXP; i++) {
            int gg = i >> 2;
            mk[i] = (gg == g0 || gg == g1) ? bi[i] : -INFINITY;
        }
        int sel[4]; float wv[4]; float wsum = 0.f;
        for (int k = 0; k < 4; k++) {
            int bmax = 0; float bv = -INFINITY;
            for (int i = 0; i < NEXP; i++) if (mk[i] > bv) { bv = mk[i]; bmax = i; }
            sel[k] = bmax; mk[bmax] = -INFINITY;
            wv[k] = sc[bmax]; wsum += sc[bmax];
        }
        float scale = SCALING / (wsum + 1e-20f);
        for (int k = 0; k < 4; k++) {
            int ee = sel[k];
            int slot = atomicAdd(&cnt[ee], 1);
            tokl[ee * T_TOK + slot] = t;
            twl[ee * T_TOK + slot] = wv[k] * scale;
            sl4[t * 4 + k] = ee * T_TOK + slot;
        }
    }
}

// ---------------- GEMM1: act = silu(Xe @ G^T) * (Xe @ U^T) ----------------
// 256x256 tile, BK=64, 8 waves (2Mx4N), deep pipeline w/ counted vmcnt.
__global__ __launch_bounds__(512, 2) void gemm1_k(const unsigned short* __restrict__ Xbf,
                                                  const unsigned short* __restrict__ wbf1,
                                                  const int* __restrict__ tokl,
                                                  const int* __restrict__ cnt,
                                                  unsigned short* __restrict__ act) {
    extern __shared__ unsigned short sm[];   // [A0|A1|B0|B1] each 256*64
    int b = blockIdx.x;
    int swz = (b & 7) * 136 + (b >> 3);      // bijective, 1088 = 8*136
    int e = swz >> 6, mt = (swz >> 3) & 7, nt = swz & 7;
    int C = (e == NEXP) ? T_TOK : cnt[e];
    int m0 = mt * 256;
    if (m0 >= C) return;
    int tid = threadIdx.x;

    int c8 = tid & 7, rr = tid >> 3;         // chunk 0..7, row 0..63
    int swzc = c8 ^ (rr & 7);
    const char* aA[4];
    const char* aB[4];
#pragma unroll
    for (int i = 0; i < 4; i++) {
        int slot = m0 + i * 64 + rr;
        int sl = (slot < C) ? slot : (C - 1);
        int tk = (e == NEXP) ? sl : tokl[e * T_TOK + sl];
        aA[i] = (const char*)Xbf + ((size_t)tk * HDIM + (size_t)swzc * 8) * 2;
        int brow = nt * 256 + i * 64 + rr;
        aB[i] = (const char*)wbf1 + (((size_t)e << 22) + (size_t)brow * HDIM + (size_t)swzc * 8) * 2;
    }

    int lane = tid & 63, wid = tid >> 6;
    int wm = wid >> 2, wn = wid & 3;         // 2M x 4N waves
    int fr = lane & 15, kg = lane >> 4;
    int xo = fr & 7;

    f32x4 acc[8][4];
#pragma unroll
    for (int m = 0; m < 8; m++)
#pragma unroll
        for (int n = 0; n < 4; n++) acc[m][n] = (f32x4){0.f, 0.f, 0.f, 0.f};

    auto stage = [&](int kt, int bf) {
        size_t kb = (size_t)kt * 128;
        char* dA = (char*)(sm + bf * 16384);
        char* dB = (char*)(sm + 32768 + bf * 16384);
#pragma unroll
        for (int i = 0; i < 4; i++) GLD_LDS16(aA[i] + kb, dA + i * 8192 + tid * 16);
#pragma unroll
        for (int i = 0; i < 4; i++) GLD_LDS16(aB[i] + kb, dB + i * 8192 + tid * 16);
    };

    stage(0, 0);
    asm volatile("s_waitcnt vmcnt(0)" ::: "memory");
    __builtin_amdgcn_s_barrier();

    const int NT = 32;                        // K = 2048 / 64
    for (int kt = 0; kt < NT; ++kt) {
        int bf = kt & 1;
        __builtin_amdgcn_s_barrier();         // all waves done reading buf bf^1
        __builtin_amdgcn_sched_barrier(0);
        if (kt + 1 < NT) {
            stage(kt + 1, bf ^ 1);
            asm volatile("s_waitcnt vmcnt(8)" ::: "memory");   // tile kt staged
        } else {
            asm volatile("s_waitcnt vmcnt(0)" ::: "memory");
        }
        __builtin_amdgcn_s_barrier();         // tile kt visible to all waves
        __builtin_amdgcn_sched_barrier(0);

        const char* lA = (const char*)(sm + bf * 16384);
        const char* lB = (const char*)(sm + 32768 + bf * 16384);
        bf16x8 bv[4][2];
#pragma unroll
        for (int n = 0; n < 4; n++)
#pragma unroll
            for (int h = 0; h < 2; h++)
                bv[n][h] = *(const bf16x8*)(lB + (wn * 64 + n * 16 + fr) * 128 + ((((h << 2) | kg) ^ xo) << 4));
#pragma unroll
        for (int p = 0; p < 4; p++) {
            bf16x8 av[2][2];
#pragma unroll
            for (int mm = 0; mm < 2; mm++)
#pragma unroll
                for (int h = 0; h < 2; h++)
                    av[mm][h] = *(const bf16x8*)(lA + (wm * 128 + (p * 2 + mm) * 16 + fr) * 128 + ((((h << 2) | kg) ^ xo) << 4));
            asm volatile("s_waitcnt lgkmcnt(0)" ::: "memory");
            __builtin_amdgcn_sched_barrier(0);
            __builtin_amdgcn_s_setprio(1);
#pragma unroll
            for (int h = 0; h < 2; h++)
#pragma unroll
                for (int n = 0; n < 4; n++) {
                    acc[p * 2 + 0][n] = __builtin_amdgcn_mfma_f32_16x16x32_bf16(av[0][h], bv[n][h], acc[p * 2 + 0][n], 0, 0, 0);
                    acc[p * 2 + 1][n] = __builtin_amdgcn_mfma_f32_16x16x32_bf16(av[1][h], bv[n][h], acc[p * 2 + 1][n], 0, 0, 0);
                }
            __builtin_amdgcn_s_setprio(0);
        }
    }

    unsigned short* actE = act + (size_t)e * T_TOK * IDIM;
#pragma unroll
    for (int m = 0; m < 8; m++)
#pragma unroll
        for (int n = 0; n < 4; n++)
#pragma unroll
            for (int q = 0; q < 4; q++) {
                float v = acc[m][n][q];
                float pu = __shfl_xor(v, 1, 64);
                int slot = m0 + wm * 128 + m * 16 + kg * 4 + q;
                if (!(lane & 1) && slot < C) {
                    float g = v, u2 = pu;
                    float a = g / (1.f + __expf(-g)) * u2;
                    int j = nt * 128 + wn * 32 + n * 8 + (fr >> 1);
                    actE[(size_t)slot * IDIM + j] = f2bf(a);
                }
            }
}

// ---------------- GEMM2: part[e][slot] = w * (act_e @ D^T) (bf16 stores) ----------
__global__ __launch_bounds__(512, 2) void gemm2_k(const unsigned short* __restrict__ act,
                                                  const unsigned short* __restrict__ wbf2,
                                                  const float* __restrict__ twl,
                                                  const int* __restrict__ cnt,
                                                  unsigned short* __restrict__ part) {
    extern __shared__ unsigned short sm[];
    int b = blockIdx.x;
    int swz = (b & 7) * 136 + (b >> 3);
    int e = swz >> 6, mt = (swz >> 3) & 7, nt = swz & 7;
    int C = (e == NEXP) ? T_TOK : cnt[e];
    int m0 = mt * 256;
    if (m0 >= C) return;
    int nb = nt * 256;
    int tid = threadIdx.x;

    const unsigned short* actE = act + (size_t)e * T_TOK * IDIM;
    int c8 = tid & 7, rr = tid >> 3;
    int swzc = c8 ^ (rr & 7);
    const char* aA[4];
    const char* aB[4];
#pragma unroll
    for (int i = 0; i < 4; i++) {
        int slot = m0 + i * 64 + rr;          // < 2048; poison rows masked in epilogue
        aA[i] = (const char*)actE + ((size_t)slot * IDIM + (size_t)swzc * 8) * 2;
        aB[i] = (const char*)wbf2 + (((size_t)e << 21) + (size_t)(nb + i * 64 + rr) * IDIM + (size_t)swzc * 8) * 2;
    }

    int lane = tid & 63, wid = tid >> 6;
    int wm = wid >> 2, wn = wid & 3;
    int fr = lane & 15, kg = lane >> 4;
    int xo = fr & 7;

    f32x4 acc[8][4];
#pragma unroll
    for (int m = 0; m < 8; m++)
#pragma unroll
        for (int n = 0; n < 4; n++) acc[m][n] = (f32x4){0.f, 0.f, 0.f, 0.f};

    auto stage = [&](int kt, int bf) {
        size_t kb = (size_t)kt * 128;
        char* dA = (char*)(sm + bf * 16384);
        char* dB = (char*)(sm + 32768 + bf * 16384);
#pragma unroll
        for (int i = 0; i < 4; i++) GLD_LDS16(aA[i] + kb, dA + i * 8192 + tid * 16);
#pragma unroll
        for (int i = 0; i < 4; i++) GLD_LDS16(aB[i] + kb, dB + i * 8192 + tid * 16);
    };

    stage(0, 0);
    asm volatile("s_waitcnt vmcnt(0)" ::: "memory");
    __builtin_amdgcn_s_barrier();

    const int NT = 16;                        // K = 1024 / 64
    for (int kt = 0; kt < NT; ++kt) {
        int bf = kt & 1;
        __builtin_amdgcn_s_barrier();
        __builtin_amdgcn_sched_barrier(0);
        if (kt + 1 < NT) {
            stage(kt + 1, bf ^ 1);
            asm volatile("s_waitcnt vmcnt(8)" ::: "memory");
        } else {
            asm volatile("s_waitcnt vmcnt(0)" ::: "memory");
        }
        __builtin_amdgcn_s_barrier();
        __builtin_amdgcn_sched_barrier(0);

        const char* lA = (const char*)(sm + bf * 16384);
        const char* lB = (const char*)(sm + 32768 + bf * 16384);
        bf16x8 bv[4][2];
#pragma unroll
        for (int n = 0; n < 4; n++)
#pragma unroll
            for (int h = 0; h < 2; h++)
                bv[n][h] = *(const bf16x8*)(lB + (wn * 64 + n * 16 + fr) * 128 + ((((h << 2) | kg) ^ xo) << 4));
#pragma unroll
        for (int p = 0; p < 4; p++) {
            bf16x8 av[2][2];
#pragma unroll
            for (int mm = 0; mm < 2; mm++)
#pragma unroll
                for (int h = 0; h < 2; h++)
                    av[mm][h] = *(const bf16x8*)(lA + (wm * 128 + (p * 2 + mm) * 16 + fr) * 128 + ((((h << 2) | kg) ^ xo) << 4));
            asm volatile("s_waitcnt lgkmcnt(0)" ::: "memory");
            __builtin_amdgcn_sched_barrier(0);
            __builtin_amdgcn_s_setprio(1);
#pragma unroll
            for (int h = 0; h < 2; h++)
#pragma unroll
                for (int n = 0; n < 4; n++) {
                    acc[p * 2 + 0][n] = __builtin_amdgcn_mfma_f32_16x16x32_bf16(av[0][h], bv[n][h], acc[p * 2 + 0][n], 0, 0, 0);
                    acc[p * 2 + 1][n] = __builtin_amdgcn_mfma_f32_16x16x32_bf16(av[1][h], bv[n][h], acc[p * 2 + 1][n], 0, 0, 0);
                }
            __builtin_amdgcn_s_setprio(0);
        }
    }

#pragma unroll
    for (int m = 0; m < 8; m++)
#pragma unroll
        for (int q = 0; q < 4; q++) {
            int slot = m0 + wm * 128 + m * 16 + kg * 4 + q;
            if (slot >= C) continue;
            float wg = (e == NEXP) ? 1.f : twl[e * T_TOK + slot];
            unsigned short* pr = part + (size_t)(e * T_TOK + slot) * HDIM + nb + wn * 64 + fr;
#pragma unroll
            for (int n = 0; n < 4; n++)
                pr[n * 16] = f2bf(wg * acc[m][n][q]);
        }
}

// ---------------- reduce: out[t] = sum of 4 routed partials + shared ----------------
__global__ __launch_bounds__(256) void reduce_k(const unsigned short* __restrict__ part,
                                                const int* __restrict__ sl4,
                                                float* __restrict__ out) {
    int t = blockIdx.x;
    int h = threadIdx.x * 8;
    int4 s = *(const int4*)(sl4 + t * 4);
    const unsigned short* p0 = part + (size_t)s.x * HDIM + h;
    const unsigned short* p1 = part + (size_t)s.y * HDIM + h;
    const unsigned short* p2 = part + (size_t)s.z * HDIM + h;
    const unsigned short* p3 = part + (size_t)s.w * HDIM + h;
    const unsigned short* p4 = part + (size_t)(NEXP * T_TOK + t) * HDIM + h;
    float o[8];
#pragma unroll
    for (int i = 0; i < 8; i++) o[i] = 0.f;
    auto addv = [&](const unsigned short* p) {
        uint4 a = *(const uint4*)p;
        const unsigned short* q = (const unsigned short*)&a;
#pragma unroll
        for (int i = 0; i < 8; i++) o[i] += __uint_as_float((uint32_t)q[i] << 16);
    };
    addv(p0); addv(p1); addv(p2); addv(p3); addv(p4);
    float4 r0 = {o[0], o[1], o[2], o[3]};
    float4 r1 = {o[4], o[5], o[6], o[7]};
    *(float4*)(out + (size_t)t * HDIM + h) = r0;
    *(float4*)(out + (size_t)t * HDIM + h + 4) = r1;
}

extern "C" void kernel_launch(void* const* d_in, const int* in_sizes, int n_in,
                              void* d_out, int out_size, void* d_ws, size_t ws_size,
                              hipStream_t stream) {
    const float* x      = (const float*)d_in[0];
    const float* gw     = (const float*)d_in[1];
    const float* bias   = (const float*)d_in[2];
    const float* gate_w = (const float*)d_in[3];
    const float* up_w   = (const float*)d_in[4];
    const float* down_w = (const float*)d_in[5];
    const float* shg    = (const float*)d_in[6];
    const float* shu    = (const float*)d_in[7];
    const float* shd    = (const float*)d_in[8];
    float* out = (float*)d_out;
    char* ws = (char*)d_ws;

    unsigned short* Xbf  = (unsigned short*)ws;                          // 8,388,608
    unsigned short* act  = (unsigned short*)(ws + 8388608ULL);           // 71,303,168
    unsigned short* wbf1 = (unsigned short*)(ws + 79691776ULL);          // 142,606,336 (reused as partials by gemm2)
    unsigned short* wbf2 = (unsigned short*)(ws + 222298112ULL);         // 71,303,168
    int*            tokl = (int*)(ws + 293601280ULL);                    // 131,072
    float*          twl  = (float*)(ws + 293732352ULL);                  // 131,072
    int*            cnt  = (int*)(ws + 293863424ULL);                    // 64
    int*            sl4  = (int*)(ws + 293863488ULL);                    // 32,768
    unsigned short* part = wbf1;                                         // alias: wbf1 dead after gemm1

    static bool attr_set = false;
    if (!attr_set) {
        hipFuncSetAttribute((const void*)gemm1_k, hipFuncAttributeMaxDynamicSharedMemorySize, 131072);
        hipFuncSetAttribute((const void*)gemm2_k, hipFuncAttributeMaxDynamicSharedMemorySize, 131072);
        attr_set = true;
    }

    hipMemsetAsync(cnt, 0, 64, stream);
    cvtw_k<<<52224, 256, 0, stream>>>(gate_w, up_w, shg, shu, down_w, shd, wbf1, wbf2);
    route2_k<<<2048, 256, 0, stream>>>(x, gw, bias, Xbf, tokl, twl, cnt, sl4);
    gemm1_k<<<1088, 512, 131072, stream>>>(Xbf, wbf1, tokl, cnt, act);
    gemm2_k<<<1088, 512, 131072, stream>>>(act, wbf2, twl, cnt, part);
    reduce_k<<<2048, 256, 0, stream>>>(part, sl4, out);
}